// Round 15
// baseline (5407.877 us; speedup 1.0000x reference)
//
#include <hip/hip_runtime.h>

// ---------------------------------------------------------------------------
// VRAE LSTM: B=512, T=512, HE=HD=512, L=64.
// Round 15: pair-interleave. Each WG (512 thr) serves TWO 16-row groups
// (A = pair p, B = pair p+16) with the SAME register-resident U slice.
// Full-width 16-row MFMA phases; f16 h exchange; flags+drain protocol.
// Stage loads of the other group issued one compute-phase early -> LLC RTTs
// hidden under compute. 16 pairs x 8 WGs = 128 WGs.
// ---------------------------------------------------------------------------

#define B_   512
#define T_   512
#define H_   512
#define WPG  8
#define RPG  16
#define UPW  64

typedef _Float16 f16;
typedef _Float16 f16x8 __attribute__((ext_vector_type(8)));
typedef _Float16 f16x4 __attribute__((ext_vector_type(4)));
typedef float f32x16 __attribute__((ext_vector_type(16)));
typedef unsigned long long u64;

#define OFF_SG_DEC 262144
#define OFF_MU_ENC 524288
#define OFF_SG_ENC 557056

__device__ __forceinline__ float sigm_(float x) { return 1.f / (1.f + __expf(-x)); }
__device__ __forceinline__ float tanh_(float x) {
  float t = fabsf(x);
  float e = __expf(2.f * t);
  float r = 1.f - 2.f / (e + 1.f);
  return x < 0.f ? -r : r;
}
__device__ __forceinline__ float softplus_(float x) {
  return fmaxf(x, 0.f) + log1pf(__expf(-fabsf(x)));
}

__global__ void pack_U(const float* __restrict__ U, f16* __restrict__ Upk) {
  const int e = blockIdx.x * 256 + threadIdx.x;
  const int j = e & 7, lane = (e >> 3) & 63, ks = (e >> 9) & 31;
  const int w = (e >> 14) & 7, wg = (e >> 17) & 7;
  const int ccol = lane & 31, khalf = lane >> 5;
  const int uu = ccol >> 2, gate = ccol & 3;
  const int k = ks * 16 + khalf * 8 + j;
  const int gcol = gate * 512 + wg * UPW + w * 8 + uu;
  Upk[e] = (f16)U[k * 2048 + gcol];
}

template <int IS_DEC>
__global__ void __launch_bounds__(512, 1)
lstm_rec(const f16* __restrict__ Upk,
         const float* __restrict__ xin,
         const float* __restrict__ wa,
         const float* __restrict__ wb,
         f16* __restrict__ hbuf,
         float* __restrict__ accmu,
         float* __restrict__ accsg,
         int* __restrict__ flags) {
  const int bid = blockIdx.x;
  const int wg = (bid >> 3) & 7;
  const int p = (bid & 7) * 2 + (bid >> 6);   // pair 0..15
  const int RA = p * 16, RB = (p + 16) * 16;
  const int tid = threadIdx.x;
  const int wave = tid >> 6, lane = tid & 63;
  const int U0 = wg * UPW;

  const int ccol = lane & 31, khalf = lane >> 5;
  f16x8 Breg[32];
#pragma unroll
  for (int ks = 0; ks < 32; ++ks) {
    const f16* ptr = Upk + (((wg * 8 + wave) * 32 + ks) << 9) + lane * 8;
    asm volatile("global_load_dwordx4 %0, %1, off\n\ts_waitcnt vmcnt(0)"
                 : "=v"(Breg[ks]) : "v"(ptr));
  }

  const int row = tid >> 4;
  const int q = (tid & 15) * 4;
  float addA[16], addB[16], xw[16], dmur[4], dstdr[4];
  if (tid < 256) {
#pragma unroll
    for (int m = 0; m < 4; ++m) {
#pragma unroll
      for (int gt = 0; gt < 4; ++gt) {
        const int col = gt * 512 + U0 + q + m;
        if (IS_DEC) {
          addA[m * 4 + gt] = xin[(RA + row) * 2048 + col];
          addB[m * 4 + gt] = xin[(RB + row) * 2048 + col];
          xw[m * 4 + gt] = 0.f;
        } else {
          addA[m * 4 + gt] = wb[col];   // bias (shared A/B)
          addB[m * 4 + gt] = wb[col];
          xw[m * 4 + gt] = wa[col];
        }
      }
      if (IS_DEC) {
        dmur[m] = wa[U0 + q + m];
        dstdr[m] = wb[U0 + q + m];
      } else {
        dmur[m] = 0.f; dstdr[m] = 0.f;
      }
    }
  }

  float cstA[4] = {0.f, 0.f, 0.f, 0.f};
  float cstB[4] = {0.f, 0.f, 0.f, 0.f};

  __shared__ __align__(16) f16 bufA[RPG * 536];
  __shared__ __align__(16) f16 bufB[RPG * 536];
  __shared__ float gatesLds[RPG * 260];
  __shared__ float xl[IS_DEC ? 4 : 32 * 516];

  if (!IS_DEC) {
#pragma unroll
    for (int i = 0; i < 32; ++i) {
      const int idx = tid + i * 512;
      const int r = idx >> 9, c2 = idx & 511;
      const int grow = (r < 16) ? (RA + r) : (RB + r - 16);
      xl[r * 516 + c2] = xin[grow * T_ + c2];
    }
  }

  int srow[4], scol[4], wof[4];
#pragma unroll
  for (int i = 0; i < 4; ++i) {
    const int w = tid + i * 512;
    srow[i] = w >> 7; scol[i] = w & 127;
    wof[i] = w;
  }
  const u64* hb64 = (const u64*)hbuf;
  const int baseA = RA * 128, baseB = RB * 128;
  const int hrow = lane & 15;

  int* const flagA = &flags[(p * WPG + wg) * 32];
  int* const flagB = &flags[((p + 16) * WPG + wg) * 32];
  const int* const gfA = &flags[(p * WPG) * 32];
  const int* const gfB = &flags[((p + 16) * WPG) * 32];

#pragma unroll
  for (int i = 0; i < 4; ++i) {
    u64 v = __hip_atomic_load(hb64 + baseA + wof[i], __ATOMIC_RELAXED,
                              __HIP_MEMORY_SCOPE_AGENT);
    *(u64*)&bufA[srow[i] * 536 + scol[i] * 4] = v;
  }
  __syncthreads();

  for (int t = 0; t < T_; ++t) {
    const int b0 = (t & 1) ? 65536 : 0;
    const int b1 = (t & 1) ? 0 : 65536;
    const int last = (t + 1 == T_);

    // ================= A phase =================
    f32x16 acc;
#pragma unroll
    for (int jj = 0; jj < 16; ++jj) acc[jj] = 0.f;
#pragma unroll
    for (int ks = 0; ks < 32; ++ks) {
      f16x8 a = *(const f16x8*)&bufA[hrow * 536 + ks * 16 + khalf * 8];
      acc = __builtin_amdgcn_mfma_f32_32x32x16_f16(a, Breg[ks], acc, 0, 0, 0);
    }
    if (t) {
      for (;;) {
        int fv = t;
        if (lane < WPG)
          fv = __hip_atomic_load(&gfB[lane * 32], __ATOMIC_RELAXED,
                                 __HIP_MEMORY_SCOPE_AGENT);
        if (__all(fv >= t)) break;
        asm volatile("s_sleep 1");
      }
    }
    u64 vB[4];
#pragma unroll
    for (int i = 0; i < 4; ++i)
      vB[i] = __hip_atomic_load(hb64 + b0 + baseB + wof[i], __ATOMIC_RELAXED,
                                __HIP_MEMORY_SCOPE_AGENT);
#pragma unroll
    for (int r = 0; r < 8; ++r) {
      const int orow = (r & 3) + 8 * (r >> 2) + 4 * khalf;
      gatesLds[orow * 260 + wave * 32 + ccol] = acc[r];
    }
    __syncthreads();  // BAR1

    float hnA[4];
    if (tid < 256) {
      float xv = 0.f;
      if (!IS_DEC) xv = xl[row * 516 + t];
#pragma unroll
      for (int m = 0; m < 4; ++m) {
        float ga[4];
#pragma unroll
        for (int gt = 0; gt < 4; ++gt) {
          float v = gatesLds[row * 260 + (q + m) * 4 + gt] + addA[m * 4 + gt];
          if (!IS_DEC) v += xv * xw[m * 4 + gt];
          ga[gt] = v;
        }
        const float cn = sigm_(ga[1]) * cstA[m] + sigm_(ga[0]) * tanh_(ga[2]);
        cstA[m] = cn;
        hnA[m] = sigm_(ga[3]) * tanh_(cn);
      }
      union { f16x4 h4; u64 u; } cv;
#pragma unroll
      for (int m = 0; m < 4; ++m) cv.h4[m] = (f16)hnA[m];
      f16* hdst = hbuf + ((t + 1) & 1) * (B_ * H_) + (RA + row) * H_ + U0 + q;
      __hip_atomic_store((u64*)hdst, cv.u, __ATOMIC_RELAXED,
                         __HIP_MEMORY_SCOPE_AGENT);
    }
#pragma unroll
    for (int i = 0; i < 4; ++i)
      *(u64*)&bufB[srow[i] * 536 + scol[i] * 4] = vB[i];
    asm volatile("s_waitcnt vmcnt(0)" ::: "memory");
    __syncthreads();  // BAR2
    if (!last && tid == 0)
      __hip_atomic_store(flagA, t + 1, __ATOMIC_RELAXED,
                         __HIP_MEMORY_SCOPE_AGENT);
    if (IS_DEC && tid < 256) {
      float pmu = 0.f, psg = 0.f;
#pragma unroll
      for (int m = 0; m < 4; ++m) {
        pmu += (float)((f16)hnA[m]) * dmur[m];
        psg += (float)((f16)hnA[m]) * dstdr[m];
      }
#pragma unroll
      for (int o = 1; o < 16; o <<= 1) {
        pmu += __shfl_xor(pmu, o);
        psg += __shfl_xor(psg, o);
      }
      if ((tid & 15) == 0) {
        unsafeAtomicAdd(&accmu[(RA + row) * T_ + t], pmu);
        unsafeAtomicAdd(&accsg[(RA + row) * T_ + t], psg);
      }
    }

    // ================= B phase =================
#pragma unroll
    for (int jj = 0; jj < 16; ++jj) acc[jj] = 0.f;
#pragma unroll
    for (int ks = 0; ks < 32; ++ks) {
      f16x8 a = *(const f16x8*)&bufB[hrow * 536 + ks * 16 + khalf * 8];
      acc = __builtin_amdgcn_mfma_f32_32x32x16_f16(a, Breg[ks], acc, 0, 0, 0);
    }
    u64 vA[4];
    if (!last) {
      for (;;) {
        int fv = t + 1;
        if (lane < WPG)
          fv = __hip_atomic_load(&gfA[lane * 32], __ATOMIC_RELAXED,
                                 __HIP_MEMORY_SCOPE_AGENT);
        if (__all(fv >= t + 1)) break;
        asm volatile("s_sleep 1");
      }
#pragma unroll
      for (int i = 0; i < 4; ++i)
        vA[i] = __hip_atomic_load(hb64 + b1 + baseA + wof[i], __ATOMIC_RELAXED,
                                  __HIP_MEMORY_SCOPE_AGENT);
    }
#pragma unroll
    for (int r = 0; r < 8; ++r) {
      const int orow = (r & 3) + 8 * (r >> 2) + 4 * khalf;
      gatesLds[orow * 260 + wave * 32 + ccol] = acc[r];
    }
    __syncthreads();  // BAR3

    float hnB[4];
    if (tid < 256) {
      float xv = 0.f;
      if (!IS_DEC) xv = xl[(16 + row) * 516 + t];
#pragma unroll
      for (int m = 0; m < 4; ++m) {
        float ga[4];
#pragma unroll
        for (int gt = 0; gt < 4; ++gt) {
          float v = gatesLds[row * 260 + (q + m) * 4 + gt] + addB[m * 4 + gt];
          if (!IS_DEC) v += xv * xw[m * 4 + gt];
          ga[gt] = v;
        }
        const float cn = sigm_(ga[1]) * cstB[m] + sigm_(ga[0]) * tanh_(ga[2]);
        cstB[m] = cn;
        hnB[m] = sigm_(ga[3]) * tanh_(cn);
      }
      union { f16x4 h4; u64 u; } cv;
#pragma unroll
      for (int m = 0; m < 4; ++m) cv.h4[m] = (f16)hnB[m];
      f16* hdst = hbuf + ((t + 1) & 1) * (B_ * H_) + (RB + row) * H_ + U0 + q;
      __hip_atomic_store((u64*)hdst, cv.u, __ATOMIC_RELAXED,
                         __HIP_MEMORY_SCOPE_AGENT);
    }
    if (!last) {
#pragma unroll
      for (int i = 0; i < 4; ++i)
        *(u64*)&bufA[srow[i] * 536 + scol[i] * 4] = vA[i];
    }
    asm volatile("s_waitcnt vmcnt(0)" ::: "memory");
    __syncthreads();  // BAR4
    if (!last && tid == 0)
      __hip_atomic_store(flagB, t + 1, __ATOMIC_RELAXED,
                         __HIP_MEMORY_SCOPE_AGENT);
    if (IS_DEC && tid < 256) {
      float pmu = 0.f, psg = 0.f;
#pragma unroll
      for (int m = 0; m < 4; ++m) {
        pmu += (float)((f16)hnB[m]) * dmur[m];
        psg += (float)((f16)hnB[m]) * dstdr[m];
      }
#pragma unroll
      for (int o = 1; o < 16; o <<= 1) {
        pmu += __shfl_xor(pmu, o);
        psg += __shfl_xor(psg, o);
      }
      if ((tid & 15) == 0) {
        unsafeAtomicAdd(&accmu[(RB + row) * T_ + t], pmu);
        unsafeAtomicAdd(&accsg[(RB + row) * T_ + t], psg);
      }
    }
  }
}

__global__ void enc_heads(const f16* __restrict__ h0, const float* __restrict__ emuW,
                          const float* __restrict__ emub, const float* __restrict__ estdW,
                          const float* __restrict__ estdb, float* __restrict__ out,
                          float* __restrict__ z) {
  const int b = blockIdx.x, tid = threadIdx.x;
  __shared__ float hrow[512];
  for (int k = tid; k < 512; k += 128)
    hrow[k] = (float)h0[b * H_ + k];
  __syncthreads();
  const int head = tid >> 6, l = tid & 63;
  const float* W = head ? estdW : emuW;
  float a = 0.f;
#pragma unroll 8
  for (int k = 0; k < 512; ++k) a += hrow[k] * W[k * 64 + l];
  if (head == 0) {
    const float v = a + emub[l];
    out[OFF_MU_ENC + b * 64 + l] = v;
    z[b * 64 + l] = v;
  } else {
    out[OFF_SG_ENC + b * 64 + l] = softplus_(a + estdb[l]);
  }
}

__global__ void dec_prep(const float* __restrict__ z, const float* __restrict__ dfsW,
                         const float* __restrict__ dfsb, const float* __restrict__ decW,
                         const float* __restrict__ decb, f16* __restrict__ hbuf,
                         float* __restrict__ zin) {
  const int b = blockIdx.x, tid = threadIdx.x;
  __shared__ float zl[64];
  if (tid < 64) zl[tid] = z[b * 64 + tid];
  __syncthreads();
  for (int c = tid; c < 512; c += 256) {
    float a = dfsb[c];
#pragma unroll
    for (int l = 0; l < 64; ++l) a += zl[l] * dfsW[l * 512 + c];
    hbuf[b * H_ + c] = (f16)tanh_(a);
  }
  for (int c = tid; c < 2048; c += 256) {
    float a = decb[c];
#pragma unroll
    for (int l = 0; l < 64; ++l) a += zl[l] * decW[l * 2048 + c];
    zin[b * 2048 + c] = a;
  }
}

__global__ void finalize_k(const float* __restrict__ accmu, const float* __restrict__ accsg,
                           const float* __restrict__ dmub, const float* __restrict__ dstdb,
                           float* __restrict__ out) {
  const int i = blockIdx.x * 256 + threadIdx.x;
  out[i] = accmu[i] + dmub[0];
  out[OFF_SG_DEC + i] = softplus_(accsg[i] + dstdb[0]);
}

extern "C" void kernel_launch(void* const* d_in, const int* in_sizes, int n_in,
                              void* d_out, int out_size, void* d_ws, size_t ws_size,
                              hipStream_t stream) {
  (void)in_sizes; (void)n_in; (void)out_size; (void)ws_size;
  const float* x     = (const float*)d_in[0];
  const float* encW  = (const float*)d_in[1];
  const float* encU  = (const float*)d_in[2];
  const float* encb  = (const float*)d_in[3];
  const float* emuW  = (const float*)d_in[4];
  const float* emub  = (const float*)d_in[5];
  const float* estdW = (const float*)d_in[6];
  const float* estdb = (const float*)d_in[7];
  const float* dfsW  = (const float*)d_in[8];
  const float* dfsb  = (const float*)d_in[9];
  const float* decW  = (const float*)d_in[10];
  const float* decU  = (const float*)d_in[11];
  const float* decb  = (const float*)d_in[12];
  const float* dmuW  = (const float*)d_in[13];
  const float* dmub  = (const float*)d_in[14];
  const float* dstdW = (const float*)d_in[15];
  const float* dstdb = (const float*)d_in[16];

  char* ws = (char*)d_ws;
  f16* hbuf    = (f16*)(ws + 0);
  float* accmu = (float*)(ws + (1u << 20));
  float* accsg = (float*)(ws + (2u << 20));
  int* flags   = (int*)(ws + (3u << 20));
  f16* UpkE    = (f16*)(ws + (3u << 20) + 65536);
  float* zin   = (float*)(ws + (3u << 20) + 65536);
  f16* UpkD    = (f16*)(ws + (7u << 20) + 65536);
  float* z     = (float*)(ws + (9u << 20) + 65536);
  float* out   = (float*)d_out;

  hipMemsetAsync(d_ws, 0, (3u << 20) + 65536, stream);

  hipLaunchKernelGGL(pack_U, dim3(4096), dim3(256), 0, stream, encU, UpkE);
  hipLaunchKernelGGL(pack_U, dim3(4096), dim3(256), 0, stream, decU, UpkD);

  hipLaunchKernelGGL((lstm_rec<0>), dim3(128), dim3(512), 0, stream,
                     UpkE, x, encW, encb, hbuf, (float*)nullptr, (float*)nullptr,
                     flags);
  hipLaunchKernelGGL(enc_heads, dim3(512), dim3(128), 0, stream,
                     hbuf, emuW, emub, estdW, estdb, out, z);
  hipLaunchKernelGGL(dec_prep, dim3(512), dim3(256), 0, stream,
                     z, dfsW, dfsb, decW, decb, hbuf, zin);
  hipLaunchKernelGGL((lstm_rec<1>), dim3(128), dim3(512), 0, stream,
                     UpkD, zin, dmuW, dstdW, hbuf, accmu, accsg, flags + 8192);
  hipLaunchKernelGGL(finalize_k, dim3(1024), dim3(256), 0, stream,
                     accmu, accsg, dmub, dstdb, out);
}

// Round 16
// 4252.704 us; speedup vs baseline: 1.2716x; 1.2716x over previous
//
#include <hip/hip_runtime.h>

// ---------------------------------------------------------------------------
// VRAE LSTM: B=512, T=512, HE=HD=512, L=64.
// FINAL = round-10 structure (best measured, 4.23 ms; rounds 11-15 all lost).
// 32 groups (16 rows) x 8 WGs (64 units, 512 thr, 8 waves). U packed f16 in
// ws, asm-loaded (resident). h: f16 [2][512][512] double buffer via relaxed
// agent atomics; sync = store-drain + per-WG flag + 8-flag s_sleep poll.
// ---------------------------------------------------------------------------

#define B_   512
#define T_   512
#define H_   512
#define NGR  32   // groups
#define WPG  8    // WGs per group
#define RPG  16   // batch rows per group
#define UPW  64   // units per WG

typedef _Float16 f16;
typedef _Float16 f16x8 __attribute__((ext_vector_type(8)));
typedef _Float16 f16x4 __attribute__((ext_vector_type(4)));
typedef float f32x16 __attribute__((ext_vector_type(16)));
typedef unsigned long long u64;

// d_out floats: mu_dec[512*512] | sg_dec[512*512] | mu_enc[512*64] | sg_enc[512*64]
#define OFF_SG_DEC 262144
#define OFF_MU_ENC 524288
#define OFF_SG_ENC 557056

__device__ __forceinline__ float sigm_(float x) { return 1.f / (1.f + __expf(-x)); }
__device__ __forceinline__ float tanh_(float x) {
  float t = fabsf(x);
  float e = __expf(2.f * t);
  float r = 1.f - 2.f / (e + 1.f);
  return x < 0.f ? -r : r;
}
__device__ __forceinline__ float softplus_(float x) {
  return fmaxf(x, 0.f) + log1pf(__expf(-fabsf(x)));
}

// ---------------------------------------------------------------------------
// Pack U [512][2048] f32 -> f16 fragment order:
// Upk[(((wg*8+w)*32+ks)<<9) + lane*8 + j] = U[ks*16+(lane>>5)*8+j][gcol],
//   gcol = gate*512 + wg*64 + w*8 + uu, uu=(lane&31)>>2, gate=lane&3.
// ---------------------------------------------------------------------------
__global__ void pack_U(const float* __restrict__ U, f16* __restrict__ Upk) {
  const int e = blockIdx.x * 256 + threadIdx.x;  // 2^20 elements exactly
  const int j = e & 7, lane = (e >> 3) & 63, ks = (e >> 9) & 31;
  const int w = (e >> 14) & 7, wg = (e >> 17) & 7;
  const int ccol = lane & 31, khalf = lane >> 5;
  const int uu = ccol >> 2, gate = ccol & 3;
  const int k = ks * 16 + khalf * 8 + j;
  const int gcol = gate * 512 + wg * UPW + w * 8 + uu;
  Upk[e] = (f16)U[k * 2048 + gcol];
}

// ---------------------------------------------------------------------------
// IS_DEC=0: xin=[B][T] input (LDS-staged once), wa=enc_W, wb=enc_b
// IS_DEC=1: xin=zin [B][2048] incl bias, wa=dmu_W, wb=dstd_W
// hbuf: [2][512][512] f16 double-buffered h; flags: [32 g][8 wg][32 ints]
// ---------------------------------------------------------------------------
template <int IS_DEC>
__global__ void __launch_bounds__(512, 1)
lstm_rec(const f16* __restrict__ Upk,
         const float* __restrict__ xin,
         const float* __restrict__ wa,
         const float* __restrict__ wb,
         f16* __restrict__ hbuf,
         float* __restrict__ accmu,
         float* __restrict__ accsg,
         int* __restrict__ flags) {
  const int bid = blockIdx.x;
  // XCD-local: a group's 8 WGs share bid%8 -> one XCD.
  const int wg = (bid >> 3) & 7;
  const int g = (bid & 7) * 4 + (bid >> 6);  // 0..31
  const int tid = threadIdx.x;
  const int wave = tid >> 6, lane = tid & 63;
  const int R0 = g * RPG;    // global batch-row base
  const int U0 = wg * UPW;   // unit base

  // ---- Breg from packed U: asm loads (non-remat, resident) ----------------
  const int ccol = lane & 31, khalf = lane >> 5;
  f16x8 Breg[32];
#pragma unroll
  for (int ks = 0; ks < 32; ++ks) {
    const f16* p = Upk + (((wg * 8 + wave) * 32 + ks) << 9) + lane * 8;
    asm volatile("global_load_dwordx4 %0, %1, off\n\ts_waitcnt vmcnt(0)"
                 : "=v"(Breg[ks]) : "v"(p));
  }

  // ---- per-thread elementwise mapping (tid<256 active) --------------------
  const int row = tid >> 4;        // 0..15 for active threads
  const int q = (tid & 15) * 4;    // first of 4 units
  float addv[16], xw[16], dmur[4], dstdr[4];
  if (tid < 256) {
#pragma unroll
    for (int m = 0; m < 4; ++m) {
#pragma unroll
      for (int gt = 0; gt < 4; ++gt) {
        const int col = gt * 512 + U0 + q + m;
        if (IS_DEC) {
          addv[m * 4 + gt] = xin[(R0 + row) * 2048 + col];
          xw[m * 4 + gt] = 0.f;
        } else {
          addv[m * 4 + gt] = wb[col];
          xw[m * 4 + gt] = wa[col];
        }
      }
      if (IS_DEC) {
        dmur[m] = wa[U0 + q + m];
        dstdr[m] = wb[U0 + q + m];
      } else {
        dmur[m] = 0.f;
        dstdr[m] = 0.f;
      }
    }
  }

  float cst[4] = {0.f, 0.f, 0.f, 0.f};

  __shared__ __align__(16) f16 hstage[RPG * 536];   // 17,152 B
  __shared__ float gatesLds[RPG * 260];             // 16,640 B
  __shared__ float pmuLds[RPG * 17];
  __shared__ float psgLds[RPG * 17];
  __shared__ float xl[RPG * 516];                   // 33,024 B (encoder x)

  if (!IS_DEC) {
    // one-time coalesced stage of x[R0..R0+16)[0..512) -> LDS
#pragma unroll
    for (int i = 0; i < 16; ++i) {
      const int idx = tid + i * 512;
      const int r = idx >> 9, c2 = idx & 511;
      xl[r * 516 + c2] = xin[(R0 + r) * T_ + c2];
    }
    __syncthreads();
  }

  const int hrow = lane & 15;  // MFMA A row
  int* const myflag = &flags[(g * WPG + wg) * 32];
  int* const grpflags = &flags[(g * WPG) * 32];

  for (int t = 0; t < T_; ++t) {
    // ------------------ stage group h tile (16KB) -> LDS -----------------
    const u64* hsrc64 = (const u64*)(hbuf + (t & 1) * (B_ * H_) + R0 * H_);
#pragma unroll
    for (int i = 0; i < 4; ++i) {
      const int w = tid + i * 512;  // 2048 u64 total; 128 u64 per row
      const int r = w >> 7, c8 = w & 127;
      u64 v = __hip_atomic_load(hsrc64 + w, __ATOMIC_RELAXED,
                                __HIP_MEMORY_SCOPE_AGENT);
      *(u64*)&hstage[r * 536 + c8 * 4] = v;
    }
    __syncthreads();

    // ------------------ gates = h @ U (MFMA 32x32x16, B in regs) ---------
    f32x16 acc;
#pragma unroll
    for (int j = 0; j < 16; ++j) acc[j] = 0.f;
#pragma unroll
    for (int ks = 0; ks < 32; ++ks) {
      f16x8 a = *(const f16x8*)&hstage[hrow * 536 + ks * 16 + khalf * 8];
      acc = __builtin_amdgcn_mfma_f32_32x32x16_f16(a, Breg[ks], acc, 0, 0, 0);
    }
    // C rows 0..15 live in regs 0..7 (row=(r&3)+8*(r>>2)+4*khalf)
#pragma unroll
    for (int r = 0; r < 8; ++r) {
      const int orow = (r & 3) + 8 * (r >> 2) + 4 * khalf;
      gatesLds[orow * 260 + wave * 32 + ccol] = acc[r];
    }
    __syncthreads();

    // ------------------ elementwise LSTM update (tid<256) ----------------
    union { f16x4 h4; u64 u; } cv;
    if (tid < 256) {
      float xv = 0.f;
      if (!IS_DEC) xv = xl[row * 516 + t];
      float hn[4];
#pragma unroll
      for (int m = 0; m < 4; ++m) {
        float ga[4];
#pragma unroll
        for (int gt = 0; gt < 4; ++gt) {
          float v = gatesLds[row * 260 + (q + m) * 4 + gt] + addv[m * 4 + gt];
          if (!IS_DEC) v += xv * xw[m * 4 + gt];
          ga[gt] = v;
        }
        const float iv = sigm_(ga[0]);
        const float fv = sigm_(ga[1]);
        const float gv = tanh_(ga[2]);
        const float ov = sigm_(ga[3]);
        const float cn = fv * cst[m] + iv * gv;
        cst[m] = cn;
        hn[m] = ov * tanh_(cn);
      }
#pragma unroll
      for (int m = 0; m < 4; ++m) cv.h4[m] = (f16)hn[m];
      f16* hdst = hbuf + ((t + 1) & 1) * (B_ * H_) + (R0 + row) * H_ + U0 + q;
      __hip_atomic_store((u64*)hdst, cv.u, __ATOMIC_RELAXED,
                         __HIP_MEMORY_SCOPE_AGENT);
      if (IS_DEC) {
        float pmu = 0.f, psg = 0.f;
#pragma unroll
        for (int m = 0; m < 4; ++m) {
          pmu += (float)cv.h4[m] * dmur[m];
          psg += (float)cv.h4[m] * dstdr[m];
        }
        pmuLds[row * 17 + (tid & 15)] = pmu;
        psgLds[row * 17 + (tid & 15)] = psg;
      }
    }

    // ------------------ release: h stores acked at LLC, then flag --------
    asm volatile("s_waitcnt vmcnt(0)" ::: "memory");
    __syncthreads();
    if (t + 1 < T_ && tid == 0)
      __hip_atomic_store(myflag, t + 1, __ATOMIC_RELAXED,
                         __HIP_MEMORY_SCOPE_AGENT);

    if (IS_DEC) {  // head partial reduction, off the critical path
      if (tid < RPG) {
        float s = 0.f;
#pragma unroll
        for (int j = 0; j < 16; ++j) s += pmuLds[tid * 17 + j];
        unsafeAtomicAdd(&accmu[(R0 + tid) * T_ + t], s);
      } else if (tid < 2 * RPG) {
        const int rr = tid - RPG;
        float s = 0.f;
#pragma unroll
        for (int j = 0; j < 16; ++j) s += psgLds[rr * 17 + j];
        unsafeAtomicAdd(&accsg[(R0 + rr) * T_ + t], s);
      }
    }

    // ------------------ group barrier: poll 8 flags (relaxed + sleep) ----
    if (t + 1 < T_) {
      if (tid < WPG) {
        while (__hip_atomic_load(&grpflags[tid * 32], __ATOMIC_RELAXED,
                                 __HIP_MEMORY_SCOPE_AGENT) < t + 1) {
          asm volatile("s_sleep 1");
        }
      }
      __syncthreads();
    }
  }
}

// ---------------------------------------------------------------------------
__global__ void enc_heads(const f16* __restrict__ h0, const float* __restrict__ emuW,
                          const float* __restrict__ emub, const float* __restrict__ estdW,
                          const float* __restrict__ estdb, float* __restrict__ out,
                          float* __restrict__ z) {
  const int b = blockIdx.x, tid = threadIdx.x;
  __shared__ float hrow[512];
  for (int k = tid; k < 512; k += 128)
    hrow[k] = (float)h0[b * H_ + k];
  __syncthreads();
  const int head = tid >> 6, l = tid & 63;
  const float* W = head ? estdW : emuW;
  float a = 0.f;
#pragma unroll 8
  for (int k = 0; k < 512; ++k) a += hrow[k] * W[k * 64 + l];
  if (head == 0) {
    const float v = a + emub[l];
    out[OFF_MU_ENC + b * 64 + l] = v;
    z[b * 64 + l] = v;
  } else {
    out[OFF_SG_ENC + b * 64 + l] = softplus_(a + estdb[l]);
  }
}

// ---------------------------------------------------------------------------
__global__ void dec_prep(const float* __restrict__ z, const float* __restrict__ dfsW,
                         const float* __restrict__ dfsb, const float* __restrict__ decW,
                         const float* __restrict__ decb, f16* __restrict__ hbuf,
                         float* __restrict__ zin) {
  const int b = blockIdx.x, tid = threadIdx.x;
  __shared__ float zl[64];
  if (tid < 64) zl[tid] = z[b * 64 + tid];
  __syncthreads();
  for (int c = tid; c < 512; c += 256) {
    float a = dfsb[c];
#pragma unroll
    for (int l = 0; l < 64; ++l) a += zl[l] * dfsW[l * 512 + c];
    hbuf[b * H_ + c] = (f16)tanh_(a);
  }
  for (int c = tid; c < 2048; c += 256) {
    float a = decb[c];
#pragma unroll
    for (int l = 0; l < 64; ++l) a += zl[l] * decW[l * 2048 + c];
    zin[b * 2048 + c] = a;
  }
}

// ---------------------------------------------------------------------------
__global__ void finalize_k(const float* __restrict__ accmu, const float* __restrict__ accsg,
                           const float* __restrict__ dmub, const float* __restrict__ dstdb,
                           float* __restrict__ out) {
  const int i = blockIdx.x * 256 + threadIdx.x;
  out[i] = accmu[i] + dmub[0];
  out[OFF_SG_DEC + i] = softplus_(accsg[i] + dstdb[0]);
}

// ---------------------------------------------------------------------------
extern "C" void kernel_launch(void* const* d_in, const int* in_sizes, int n_in,
                              void* d_out, int out_size, void* d_ws, size_t ws_size,
                              hipStream_t stream) {
  (void)in_sizes; (void)n_in; (void)out_size; (void)ws_size;
  const float* x     = (const float*)d_in[0];
  const float* encW  = (const float*)d_in[1];
  const float* encU  = (const float*)d_in[2];
  const float* encb  = (const float*)d_in[3];
  const float* emuW  = (const float*)d_in[4];
  const float* emub  = (const float*)d_in[5];
  const float* estdW = (const float*)d_in[6];
  const float* estdb = (const float*)d_in[7];
  const float* dfsW  = (const float*)d_in[8];
  const float* dfsb  = (const float*)d_in[9];
  const float* decW  = (const float*)d_in[10];
  const float* decU  = (const float*)d_in[11];
  const float* decb  = (const float*)d_in[12];
  const float* dmuW  = (const float*)d_in[13];
  const float* dmub  = (const float*)d_in[14];
  const float* dstdW = (const float*)d_in[15];
  const float* dstdb = (const float*)d_in[16];

  char* ws = (char*)d_ws;
  f16* hbuf    = (f16*)(ws + 0);                        // 1 MB [2][512][512]
  float* accmu = (float*)(ws + (1u << 20));             // 1 MB
  float* accsg = (float*)(ws + (2u << 20));             // 1 MB
  int* flags   = (int*)(ws + (3u << 20));               // 64 KB (2 phases)
  f16* UpkE    = (f16*)(ws + (3u << 20) + 65536);       // 2 MB (dead post-enc)
  float* zin   = (float*)(ws + (3u << 20) + 65536);     // 4 MB (overlays UpkE)
  f16* UpkD    = (f16*)(ws + (7u << 20) + 65536);       // 2 MB
  float* z     = (float*)(ws + (9u << 20) + 65536);     // 128 KB
  float* out   = (float*)d_out;

  // zero hbuf/acc/flags (must be re-done every launch)
  hipMemsetAsync(d_ws, 0, (3u << 20) + 65536, stream);

  hipLaunchKernelGGL(pack_U, dim3(4096), dim3(256), 0, stream, encU, UpkE);
  hipLaunchKernelGGL(pack_U, dim3(4096), dim3(256), 0, stream, decU, UpkD);

  hipLaunchKernelGGL((lstm_rec<0>), dim3(256), dim3(512), 0, stream,
                     UpkE, x, encW, encb, hbuf, (float*)nullptr, (float*)nullptr,
                     flags);
  hipLaunchKernelGGL(enc_heads, dim3(512), dim3(128), 0, stream,
                     hbuf, emuW, emub, estdW, estdb, out, z);
  hipLaunchKernelGGL(dec_prep, dim3(512), dim3(256), 0, stream,
                     z, dfsW, dfsb, decW, decb, hbuf, zin);
  hipLaunchKernelGGL((lstm_rec<1>), dim3(256), dim3(512), 0, stream,
                     UpkD, zin, dmuW, dstdW, hbuf, accmu, accsg, flags + 8192);
  hipLaunchKernelGGL(finalize_k, dim3(1024), dim3(256), 0, stream,
                     accmu, accsg, dmub, dstdb, out);
}